// Round 11
// baseline (211.849 us; speedup 1.0000x reference)
//
#include <hip/hip_runtime.h>

#define N_NODES 50000
#define N_EDGES 800000
// IN=HID=64, OUT=16, N_RELS=16, N_BASES=4 (hard-coded below)

typedef __attribute__((ext_vector_type(8))) short bf16x8;
typedef __attribute__((ext_vector_type(4))) float f32x4;

// ---- bf16 helpers (RNE pack, shift-unpack) --------------------------------
__device__ __forceinline__ unsigned bf16rne(float x) {
  unsigned u = __float_as_uint(x);
  return (u + 0x7FFFu + ((u >> 16) & 1u)) >> 16;
}
__device__ __forceinline__ unsigned packbf2(float a, float b) {
  return bf16rne(a) | (bf16rne(b) << 16);
}
__device__ __forceinline__ float bflo(unsigned u) { return __uint_as_float(u << 16); }
__device__ __forceinline__ float bfhi(unsigned u) { return __uint_as_float(u & 0xFFFF0000u); }

// ===========================================================================
// Merged prep + histogram (feats float4 count == N_EDGES == 800000).
// Block 3125 builds bf16 B-matrices: b1T[o][q] (64x256), b2p[j=o*4+b][k].
// ===========================================================================
__global__ __launch_bounds__(256) void k_prep_hist(
    const float4* __restrict__ feats4, uint2* __restrict__ xbf,
    const float* __restrict__ bases1, const float* __restrict__ bases2,
    unsigned short* __restrict__ b1T, unsigned short* __restrict__ b2p,
    const int* __restrict__ dst, int* __restrict__ deg,
    int* __restrict__ rank) {
  if (blockIdx.x < 3125) {
    const int i = blockIdx.x * 256 + threadIdx.x;  // < 800000
    float4 v = feats4[i];
    xbf[i] = make_uint2(packbf2(v.x, v.y), packbf2(v.z, v.w));
    rank[i] = atomicAdd(&deg[dst[i]], 1);
  } else {
    for (int idx = threadIdx.x; idx < 64 * 256; idx += 256) {
      int o = idx >> 8, q = idx & 255;
      b1T[idx] = (unsigned short)bf16rne(bases1[q * 64 + o]);
    }
    for (int idx = threadIdx.x; idx < 64 * 64; idx += 256) {
      int j = idx >> 6, k = idx & 63;
      int o = j >> 2, b = j & 3;
      b2p[idx] = (unsigned short)bf16rne(bases2[b * 1024 + k * 16 + o]);
    }
  }
}

// ===========================================================================
// Hierarchical exclusive scan -> rowp.
// ===========================================================================
__global__ __launch_bounds__(1024) void k_scan1(const int* __restrict__ deg,
                                                int* __restrict__ rowp,
                                                int* __restrict__ bsum) {
  __shared__ int wsum[16];
  const int tid = threadIdx.x, lane = tid & 63, wid = tid >> 6;
  const int i = blockIdx.x * 1024 + tid;
  int v = (i < N_NODES) ? deg[i] : 0;
  int incl = v;
#pragma unroll
  for (int off = 1; off < 64; off <<= 1) {
    int t = __shfl_up(incl, off, 64);
    if (lane >= off) incl += t;
  }
  if (lane == 63) wsum[wid] = incl;
  __syncthreads();
  if (tid < 16) {
    int wi = wsum[tid];
#pragma unroll
    for (int off = 1; off < 16; off <<= 1) {
      int t = __shfl_up(wi, off, 64);
      if (lane >= off) wi += t;
    }
    wsum[tid] = wi;
  }
  __syncthreads();
  int woff = (wid > 0) ? wsum[wid - 1] : 0;
  int incl_all = incl + woff;
  if (i < N_NODES) rowp[i + 1] = incl_all;
  if (tid == 1023) bsum[blockIdx.x] = incl_all;
}

__global__ __launch_bounds__(1024) void k_scan3(int* __restrict__ rowp,
                                                const int* __restrict__ bsum,
                                                int nblk) {
  __shared__ int s_off;
  const int tid = threadIdx.x;
  if (tid < 64) {
    int v = (tid < nblk && tid < blockIdx.x) ? bsum[tid] : 0;
#pragma unroll
    for (int off = 32; off >= 1; off >>= 1) v += __shfl_down(v, off, 64);
    if (tid == 0) s_off = v;
  }
  __syncthreads();
  const int i = blockIdx.x * 1024 + tid;
  if (i < N_NODES) rowp[i + 1] += s_off;
  if (i == 0) rowp[0] = 0;
}

// 8 B records: (src | ety<<16, norm fp32 bits) into dst-sorted order.
__global__ __launch_bounds__(256) void k_scatter(
    const int* __restrict__ src, const int* __restrict__ dst,
    const int* __restrict__ ety, const float* __restrict__ enorm,
    const int* __restrict__ rowp, const int* __restrict__ rank,
    uint2* __restrict__ s_edge) {
  int e = blockIdx.x * 256 + threadIdx.x;
  if (e >= N_EDGES) return;
  const int pos = rowp[dst[e]] + rank[e];
  s_edge[pos] = make_uint2((unsigned)src[e] | ((unsigned)ety[e] << 16),
                           __float_as_uint(enorm[e]));
}

// ===========================================================================
// Gather one node's u into the MFMA A-tile (bf16), fp32 accumulate.
// Wave = node; eslot = lane>>4, ch4 = lane&15 (channels 4ch4..+3, 8 B load).
// 2-AHEAD pipeline: rec fetched at distance 2, x at distance 1 using the rec
// that arrived last iteration -> rec->x dependency is off the critical path.
// ===========================================================================
#define ROWB 264
__device__ __forceinline__ void gather_node(
    const int* __restrict__ rowp, const uint2* __restrict__ s_edge,
    const uint2* __restrict__ xv, const float4* __restrict__ coefLDS,
    unsigned short* __restrict__ uA, int node, int m, int lane) {
  const int eslot = lane >> 4, ch4 = lane & 15;
  const int beg = rowp[node], end = rowp[node + 1];
  float4 a0 = {0, 0, 0, 0}, a1 = {0, 0, 0, 0}, a2 = {0, 0, 0, 0}, a3 = {0, 0, 0, 0};
  int j = beg + eslot;
  uint2 rec0 = {0, 0}, rec1 = {0, 0}, xp = {0, 0};
  if (j < end) rec0 = s_edge[j];
  if (j + 4 < end) rec1 = s_edge[j + 4];
  if (j < end) xp = xv[(rec0.x & 0xFFFF) * 16 + ch4];
  while (j < end) {
    uint2 rec2 = {0, 0}, xp1 = {0, 0};
    if (j + 8 < end) rec2 = s_edge[j + 8];
    if (j + 4 < end) xp1 = xv[(rec1.x & 0xFFFF) * 16 + ch4];
    const float nm = __uint_as_float(rec0.y);
    const float4 c = coefLDS[rec0.x >> 16];
    const float w0 = nm * c.x, w1 = nm * c.y, w2 = nm * c.z, w3 = nm * c.w;
    const float x0 = bflo(xp.x), x1 = bfhi(xp.x), x2 = bflo(xp.y), x3 = bfhi(xp.y);
    a0.x += w0 * x0; a0.y += w0 * x1; a0.z += w0 * x2; a0.w += w0 * x3;
    a1.x += w1 * x0; a1.y += w1 * x1; a1.z += w1 * x2; a1.w += w1 * x3;
    a2.x += w2 * x0; a2.y += w2 * x1; a2.z += w2 * x2; a2.w += w2 * x3;
    a3.x += w3 * x0; a3.y += w3 * x1; a3.z += w3 * x2; a3.w += w3 * x3;
    j += 4; rec0 = rec1; rec1 = rec2; xp = xp1;
  }
#define RED1(x) x += __shfl_down(x, 32, 64); x += __shfl_down(x, 16, 64)
  RED1(a0.x); RED1(a0.y); RED1(a0.z); RED1(a0.w);
  RED1(a1.x); RED1(a1.y); RED1(a1.z); RED1(a1.w);
  RED1(a2.x); RED1(a2.y); RED1(a2.z); RED1(a2.w);
  RED1(a3.x); RED1(a3.y); RED1(a3.z); RED1(a3.w);
#undef RED1
  if (eslot == 0) {
    unsigned short* row = uA + m * ROWB + 4 * ch4;
    *(uint2*)(row + 0 * 64) = make_uint2(packbf2(a0.x, a0.y), packbf2(a0.z, a0.w));
    *(uint2*)(row + 1 * 64) = make_uint2(packbf2(a1.x, a1.y), packbf2(a1.z, a1.w));
    *(uint2*)(row + 2 * 64) = make_uint2(packbf2(a2.x, a2.y), packbf2(a2.z, a2.w));
    *(uint2*)(row + 3 * 64) = make_uint2(packbf2(a3.x, a3.y), packbf2(a3.z, a3.w));
  }
}

// ===========================================================================
// Fused layer 1 + Y2 pre-transform: 16 nodes/block, 16 waves (1024 threads).
// WAVE-PER-NODE gather: each wave gathers exactly one node -> per-block
// serial gather chain drops from ~19 pipelined iterations (4 nodes
// sequential per wave) to ~max(deg)/4 ~ 7. 2 blocks/CU -> 32 waves/CU.
// Phase B (MFMA1 h1 = relu(uA@B1+bias); MFMA2 Y2 = h1@b2p) on waves 0-3;
// barriers are unconditional.
// ===========================================================================
__global__ __launch_bounds__(1024, 8) void k_l1_fused(
    const int* __restrict__ rowp, const uint2* __restrict__ s_edge,
    const uint2* __restrict__ xbf, const float* __restrict__ coef1,
    const unsigned short* __restrict__ b1T,  // [64][256] bf16
    const float* __restrict__ bias1,         // [64]
    const unsigned short* __restrict__ b2p,  // [64][64] bf16
    uint2* __restrict__ y2bf) {              // [N][16] uint2 = [N][64] bf16
  __shared__ __align__(16) unsigned short uA[16 * ROWB];  // 8.25 KB
  __shared__ float coefs[64];
  __shared__ float cmat[16 * 68];  // 4.25 KB
  const int wid = threadIdx.x >> 6, lane = threadIdx.x & 63;
  if (threadIdx.x < 64) coefs[threadIdx.x] = coef1[threadIdx.x];
  __syncthreads();
  const int nbase = blockIdx.x * 16;
  // Each wave gathers its own node into uA row wid.
  gather_node(rowp, s_edge, xbf, (const float4*)coefs, uA, nbase + wid, wid,
              lane);
  __syncthreads();
  const int nloc = lane & 15, kgrp = lane >> 4;
  f32x4 acc1 = {0.f, 0.f, 0.f, 0.f};
  if (wid < 4) {
    // MFMA1: wave wid handles o-tile wid (o = 16*wid .. +15).
#pragma unroll
    for (int ks = 0; ks < 8; ++ks) {
      const int k0 = ks * 32 + kgrp * 8;
      const bf16x8 a = *(const bf16x8*)&uA[nloc * ROWB + k0];
      const bf16x8 b = *(const bf16x8*)&b1T[(wid * 16 + nloc) * 256 + k0];
      acc1 = __builtin_amdgcn_mfma_f32_16x16x32_bf16(a, b, acc1, 0, 0, 0);
    }
    const int o = wid * 16 + nloc;
    const float bs = bias1[o];
#pragma unroll
    for (int r = 0; r < 4; ++r) {
      const int m = (lane >> 4) * 4 + r;
      cmat[m * 68 + o] = fmaxf(acc1[r] + bs, 0.f);
    }
  }
  __syncthreads();
  // MFMA2: Y2 = h1 @ b2p. Wave wid handles j-tile wid (j = 16*wid .. +15).
  f32x4 acc2 = {0.f, 0.f, 0.f, 0.f};
  if (wid < 4) {
#pragma unroll
    for (int ks = 0; ks < 2; ++ks) {
      const int k0 = ks * 32 + kgrp * 8;
      const float4 c0 = *(const float4*)&cmat[nloc * 68 + k0];
      const float4 c1 = *(const float4*)&cmat[nloc * 68 + k0 + 4];
      union { bf16x8 v; unsigned u[4]; } au;
      au.u[0] = packbf2(c0.x, c0.y); au.u[1] = packbf2(c0.z, c0.w);
      au.u[2] = packbf2(c1.x, c1.y); au.u[3] = packbf2(c1.z, c1.w);
      const bf16x8 b = *(const bf16x8*)&b2p[(wid * 16 + nloc) * 64 + k0];
      acc2 = __builtin_amdgcn_mfma_f32_16x16x32_bf16(au.v, b, acc2, 0, 0, 0);
    }
  }
  __syncthreads();  // cmat reads done; reuse as Y2 staging
  if (wid < 4) {
#pragma unroll
    for (int r = 0; r < 4; ++r) {
      const int m = (lane >> 4) * 4 + r;
      cmat[m * 68 + wid * 16 + nloc] = acc2[r];
    }
  }
  __syncthreads();
  if (threadIdx.x < 256) {
    const int nl = threadIdx.x >> 4, c4 = threadIdx.x & 15;
    const float* cr = &cmat[nl * 68 + 4 * c4];
    y2bf[(size_t)(nbase + nl) * 16 + c4] =
        make_uint2(packbf2(cr[0], cr[1]), packbf2(cr[2], cr[3]));
  }
}

// ===========================================================================
// Layer 2 (slim, widened):
// out[d][o] = relu(bias2[o] + sum_{e->d} nm_e * dot(coef2[t_e], Y2[src][o][:]))
// Wave = 2 nodes interleaved; lane = (eslot = lane>>3 in [0,8), og = lane&7).
// Each lane loads one uint4 (2 output channels x 4 bases) -> 8 edge streams.
// ===========================================================================
__global__ __launch_bounds__(256) void k_l2_gather(
    const int* __restrict__ rowp, const uint2* __restrict__ s_edge,
    const uint4* __restrict__ y2v,   // [N][8] uint4
    const float* __restrict__ coef2, const float* __restrict__ bias2,
    float2* __restrict__ out) {      // [N][8] float2
  __shared__ float coefs[64];
  if (threadIdx.x < 64) coefs[threadIdx.x] = coef2[threadIdx.x];
  __syncthreads();
  const float4* coefv = (const float4*)coefs;
  const int wid = threadIdx.x >> 6, lane = threadIdx.x & 63;
  const int eslot = lane >> 3, og = lane & 7;
  const int nbase = blockIdx.x * 8 + wid * 2;

  int j[2], jend[2];
  float a0[2] = {0.f, 0.f}, a1[2] = {0.f, 0.f};
  uint2 r0[2], r1[2];
  uint4 yp[2];
#pragma unroll
  for (int m = 0; m < 2; ++m) {
    const int node = nbase + m;
    const int beg = rowp[node];
    jend[m] = rowp[node + 1];
    j[m] = beg + eslot;
    r0[m] = make_uint2(0, 0); r1[m] = make_uint2(0, 0);
    yp[m] = make_uint4(0, 0, 0, 0);
    if (j[m] < jend[m]) r0[m] = s_edge[j[m]];
    if (j[m] + 8 < jend[m]) r1[m] = s_edge[j[m] + 8];
  }
#pragma unroll
  for (int m = 0; m < 2; ++m)
    if (j[m] < jend[m]) yp[m] = y2v[(r0[m].x & 0xFFFF) * 8 + og];

  while ((j[0] < jend[0]) | (j[1] < jend[1])) {
#pragma unroll
    for (int m = 0; m < 2; ++m) {
      uint2 r2 = make_uint2(0, 0);
      uint4 yp1 = make_uint4(0, 0, 0, 0);
      if (j[m] + 16 < jend[m]) r2 = s_edge[j[m] + 16];
      if (j[m] + 8 < jend[m]) yp1 = y2v[(r1[m].x & 0xFFFF) * 8 + og];
      if (j[m] < jend[m]) {
        const float nm = __uint_as_float(r0[m].y);
        const float4 c = coefv[r0[m].x >> 16];
        a0[m] += nm * (c.x * bflo(yp[m].x) + c.y * bfhi(yp[m].x) +
                       c.z * bflo(yp[m].y) + c.w * bfhi(yp[m].y));
        a1[m] += nm * (c.x * bflo(yp[m].z) + c.y * bfhi(yp[m].z) +
                       c.z * bflo(yp[m].w) + c.w * bfhi(yp[m].w));
      }
      j[m] += 8; r0[m] = r1[m]; r1[m] = r2; yp[m] = yp1;
    }
  }
#pragma unroll
  for (int m = 0; m < 2; ++m) {
    a0[m] += __shfl_down(a0[m], 32, 64);
    a0[m] += __shfl_down(a0[m], 16, 64);
    a0[m] += __shfl_down(a0[m], 8, 64);
    a1[m] += __shfl_down(a1[m], 32, 64);
    a1[m] += __shfl_down(a1[m], 16, 64);
    a1[m] += __shfl_down(a1[m], 8, 64);
  }
  if (eslot == 0) {
    const float b0 = bias2[2 * og], b1 = bias2[2 * og + 1];
#pragma unroll
    for (int m = 0; m < 2; ++m) {
      out[(size_t)(nbase + m) * 8 + og] =
          make_float2(fmaxf(a0[m] + b0, 0.f), fmaxf(a1[m] + b1, 0.f));
    }
  }
}

extern "C" void kernel_launch(void* const* d_in, const int* in_sizes, int n_in,
                              void* d_out, int out_size, void* d_ws, size_t ws_size,
                              hipStream_t stream) {
  const float* feats  = (const float*)d_in[0];
  const int*   src    = (const int*)d_in[1];
  const int*   dst    = (const int*)d_in[2];
  const int*   etype  = (const int*)d_in[3];
  const float* enorm  = (const float*)d_in[4];
  const float* bases1 = (const float*)d_in[5];
  const float* coef1  = (const float*)d_in[6];
  const float* bias1  = (const float*)d_in[7];
  const float* bases2 = (const float*)d_in[8];
  const float* coef2  = (const float*)d_in[9];
  const float* bias2  = (const float*)d_in[10];

  // Workspace (~23 MB): xbf | y2bf | s_edge | rank | b1T | b2p | deg | rowp | bsum
  uint2* xbf    = (uint2*)d_ws;                       // N*16 uint2 (6.4 MB)
  uint2* y2bf   = xbf + (size_t)N_NODES * 16;         // N*16 uint2 (6.4 MB)
  uint2* s_edge = y2bf + (size_t)N_NODES * 16;        // E uint2 (6.4 MB)
  int*   rank   = (int*)(s_edge + N_EDGES);           // E ints (3.2 MB)
  unsigned short* b1T = (unsigned short*)(rank + N_EDGES);  // 16384 (32 KB)
  unsigned short* b2p = b1T + 64 * 256;               // 4096 (8 KB)
  int*   deg    = (int*)(b2p + 64 * 64);              // N
  int*   rowp   = deg + N_NODES;                      // N+1
  int*   bsum   = rowp + N_NODES + 1;                 // 64

  const int SCAN_BLKS = (N_NODES + 1023) / 1024;  // 49

  hipMemsetAsync(deg, 0, N_NODES * sizeof(int), stream);

  k_prep_hist<<<3126, 256, 0, stream>>>((const float4*)feats, xbf, bases1,
                                        bases2, b1T, b2p, dst, deg, rank);
  k_scan1<<<SCAN_BLKS, 1024, 0, stream>>>(deg, rowp, bsum);
  k_scan3<<<SCAN_BLKS, 1024, 0, stream>>>(rowp, bsum, SCAN_BLKS);
  k_scatter<<<N_EDGES / 256, 256, 0, stream>>>(src, dst, etype, enorm,
                                               rowp, rank, s_edge);
  k_l1_fused<<<N_NODES / 16, 1024, 0, stream>>>(rowp, s_edge, xbf, coef1,
                                                b1T, bias1, b2p, y2bf);
  k_l2_gather<<<N_NODES / 8, 256, 0, stream>>>(rowp, s_edge,
                                               (const uint4*)y2bf, coef2,
                                               bias2, (float2*)d_out);
}

// Round 12
// 200.370 us; speedup vs baseline: 1.0573x; 1.0573x over previous
//
#include <hip/hip_runtime.h>

#define N_NODES 50000
#define N_EDGES 800000
// IN=HID=64, OUT=16, N_RELS=16, N_BASES=4 (hard-coded below)

typedef __attribute__((ext_vector_type(8))) short bf16x8;
typedef __attribute__((ext_vector_type(4))) float f32x4;

// ---- bf16 helpers (RNE pack, shift-unpack) --------------------------------
__device__ __forceinline__ unsigned bf16rne(float x) {
  unsigned u = __float_as_uint(x);
  return (u + 0x7FFFu + ((u >> 16) & 1u)) >> 16;
}
__device__ __forceinline__ unsigned packbf2(float a, float b) {
  return bf16rne(a) | (bf16rne(b) << 16);
}
__device__ __forceinline__ float bflo(unsigned u) { return __uint_as_float(u << 16); }
__device__ __forceinline__ float bfhi(unsigned u) { return __uint_as_float(u & 0xFFFF0000u); }

// ===========================================================================
// Merged prep + histogram (feats float4 count == N_EDGES == 800000).
// Block 3125 builds bf16 B-matrices: b1T[o][q] (64x256), b2p[j=o*4+b][k].
// ===========================================================================
__global__ __launch_bounds__(256) void k_prep_hist(
    const float4* __restrict__ feats4, uint2* __restrict__ xbf,
    const float* __restrict__ bases1, const float* __restrict__ bases2,
    unsigned short* __restrict__ b1T, unsigned short* __restrict__ b2p,
    const int* __restrict__ dst, int* __restrict__ deg,
    int* __restrict__ rank) {
  if (blockIdx.x < 3125) {
    const int i = blockIdx.x * 256 + threadIdx.x;  // < 800000
    float4 v = feats4[i];
    xbf[i] = make_uint2(packbf2(v.x, v.y), packbf2(v.z, v.w));
    rank[i] = atomicAdd(&deg[dst[i]], 1);
  } else {
    for (int idx = threadIdx.x; idx < 64 * 256; idx += 256) {
      int o = idx >> 8, q = idx & 255;
      b1T[idx] = (unsigned short)bf16rne(bases1[q * 64 + o]);
    }
    for (int idx = threadIdx.x; idx < 64 * 64; idx += 256) {
      int j = idx >> 6, k = idx & 63;
      int o = j >> 2, b = j & 3;
      b2p[idx] = (unsigned short)bf16rne(bases2[b * 1024 + k * 16 + o]);
    }
  }
}

// ===========================================================================
// Hierarchical exclusive scan -> rowp.
// ===========================================================================
__global__ __launch_bounds__(1024) void k_scan1(const int* __restrict__ deg,
                                                int* __restrict__ rowp,
                                                int* __restrict__ bsum) {
  __shared__ int wsum[16];
  const int tid = threadIdx.x, lane = tid & 63, wid = tid >> 6;
  const int i = blockIdx.x * 1024 + tid;
  int v = (i < N_NODES) ? deg[i] : 0;
  int incl = v;
#pragma unroll
  for (int off = 1; off < 64; off <<= 1) {
    int t = __shfl_up(incl, off, 64);
    if (lane >= off) incl += t;
  }
  if (lane == 63) wsum[wid] = incl;
  __syncthreads();
  if (tid < 16) {
    int wi = wsum[tid];
#pragma unroll
    for (int off = 1; off < 16; off <<= 1) {
      int t = __shfl_up(wi, off, 64);
      if (lane >= off) wi += t;
    }
    wsum[tid] = wi;
  }
  __syncthreads();
  int woff = (wid > 0) ? wsum[wid - 1] : 0;
  int incl_all = incl + woff;
  if (i < N_NODES) rowp[i + 1] = incl_all;
  if (tid == 1023) bsum[blockIdx.x] = incl_all;
}

__global__ __launch_bounds__(1024) void k_scan3(int* __restrict__ rowp,
                                                const int* __restrict__ bsum,
                                                int nblk) {
  __shared__ int s_off;
  const int tid = threadIdx.x;
  if (tid < 64) {
    int v = (tid < nblk && tid < blockIdx.x) ? bsum[tid] : 0;
#pragma unroll
    for (int off = 32; off >= 1; off >>= 1) v += __shfl_down(v, off, 64);
    if (tid == 0) s_off = v;
  }
  __syncthreads();
  const int i = blockIdx.x * 1024 + tid;
  if (i < N_NODES) rowp[i + 1] += s_off;
  if (i == 0) rowp[0] = 0;
}

// ===========================================================================
// 4 B records: src(16b) | ety(4b) | norm 12-bit fixed-point (err <= 2.4e-4,
// far below the bf16 pipeline noise). Halves the random scatter-write
// payload and the gather rec-load bytes.
// ===========================================================================
__global__ __launch_bounds__(256) void k_scatter(
    const int* __restrict__ src, const int* __restrict__ dst,
    const int* __restrict__ ety, const float* __restrict__ enorm,
    const int* __restrict__ rowp, const int* __restrict__ rank,
    unsigned* __restrict__ s_edge) {
  int e = blockIdx.x * 256 + threadIdx.x;
  if (e >= N_EDGES) return;
  const int pos = rowp[dst[e]] + rank[e];
  unsigned nq = (unsigned)(enorm[e] * 4096.f + 0.5f);
  nq = nq > 4095u ? 4095u : nq;
  s_edge[pos] = (unsigned)src[e] | ((unsigned)ety[e] << 16) | (nq << 20);
}

#define NMSCALE (1.f / 4096.f)

// ===========================================================================
// Gather one node's u into a 2-SLAB MFMA A-tile (bf16), fp32 accumulate.
// Wave = node; eslot = lane>>4, ch4 = lane&15 (channels 4ch4..+3, 8 B load).
// 2-ahead pipeline (rec at distance 2, x at distance 1).
// Slab s = eslot&1 holds partials of eslots {s, s+2}: cross-pair reduce is a
// single shfl_down(32) stage (half of R10's butterfly); pack runs on 32
// lanes. MFMA accumulates over both slabs reusing the B fragment.
// ===========================================================================
#define ROWB 264
__device__ __forceinline__ void gather_node(
    const int* __restrict__ rowp, const unsigned* __restrict__ s_edge,
    const uint2* __restrict__ xv, const float4* __restrict__ coefLDS,
    unsigned short* __restrict__ uA,  // [2][16][ROWB]
    int node, int m, int lane) {
  const int eslot = lane >> 4, ch4 = lane & 15;
  const int beg = rowp[node], end = rowp[node + 1];
  float4 a0 = {0, 0, 0, 0}, a1 = {0, 0, 0, 0}, a2 = {0, 0, 0, 0}, a3 = {0, 0, 0, 0};
  int j = beg + eslot;
  unsigned rec0 = 0, rec1 = 0;
  uint2 xp = {0, 0};
  if (j < end) rec0 = s_edge[j];
  if (j + 4 < end) rec1 = s_edge[j + 4];
  if (j < end) xp = xv[(rec0 & 0xFFFF) * 16 + ch4];
  while (j < end) {
    unsigned rec2 = 0;
    uint2 xp1 = {0, 0};
    if (j + 8 < end) rec2 = s_edge[j + 8];
    if (j + 4 < end) xp1 = xv[(rec1 & 0xFFFF) * 16 + ch4];
    const float nm = (float)(rec0 >> 20) * NMSCALE;
    const float4 c = coefLDS[(rec0 >> 16) & 15];
    const float w0 = nm * c.x, w1 = nm * c.y, w2 = nm * c.z, w3 = nm * c.w;
    const float x0 = bflo(xp.x), x1 = bfhi(xp.x), x2 = bflo(xp.y), x3 = bfhi(xp.y);
    a0.x += w0 * x0; a0.y += w0 * x1; a0.z += w0 * x2; a0.w += w0 * x3;
    a1.x += w1 * x0; a1.y += w1 * x1; a1.z += w1 * x2; a1.w += w1 * x3;
    a2.x += w2 * x0; a2.y += w2 * x1; a2.z += w2 * x2; a2.w += w2 * x3;
    a3.x += w3 * x0; a3.y += w3 * x1; a3.z += w3 * x2; a3.w += w3 * x3;
    j += 4; rec0 = rec1; rec1 = rec2; xp = xp1;
  }
  // Combine eslot pairs {e, e+2}: one butterfly stage (results on eslot 0,1).
#define RED1(x) x += __shfl_down(x, 32, 64)
  RED1(a0.x); RED1(a0.y); RED1(a0.z); RED1(a0.w);
  RED1(a1.x); RED1(a1.y); RED1(a1.z); RED1(a1.w);
  RED1(a2.x); RED1(a2.y); RED1(a2.z); RED1(a2.w);
  RED1(a3.x); RED1(a3.y); RED1(a3.z); RED1(a3.w);
#undef RED1
  if (eslot < 2) {
    unsigned short* row = uA + (eslot * 16 + m) * ROWB + 4 * ch4;
    *(uint2*)(row + 0 * 64) = make_uint2(packbf2(a0.x, a0.y), packbf2(a0.z, a0.w));
    *(uint2*)(row + 1 * 64) = make_uint2(packbf2(a1.x, a1.y), packbf2(a1.z, a1.w));
    *(uint2*)(row + 2 * 64) = make_uint2(packbf2(a2.x, a2.y), packbf2(a2.z, a2.w));
    *(uint2*)(row + 3 * 64) = make_uint2(packbf2(a3.x, a3.y), packbf2(a3.z, a3.w));
  }
}

// ===========================================================================
// Fused layer 1 + Y2 pre-transform: 16 nodes/block, 4 waves (R10 shape).
//   gather -> uA[2][16][256] bf16 (2 slabs)
//   MFMA1: acc += uA_s0@B1 + uA_s1@B1 (B frag reused; 16 MFMA/wave)
//   MFMA2 [16x64]@[64x64]: Y2 = h1 @ b2p
// ===========================================================================
__global__ __launch_bounds__(256) void k_l1_fused(
    const int* __restrict__ rowp, const unsigned* __restrict__ s_edge,
    const uint2* __restrict__ xbf, const float* __restrict__ coef1,
    const unsigned short* __restrict__ b1T,  // [64][256] bf16
    const float* __restrict__ bias1,         // [64]
    const unsigned short* __restrict__ b2p,  // [64][64] bf16
    uint2* __restrict__ y2bf) {              // [N][16] uint2 = [N][64] bf16
  __shared__ __align__(16) unsigned short uA[2 * 16 * ROWB];  // 16.5 KB
  __shared__ float coefs[64];
  __shared__ float cmat[16 * 68];  // 4.25 KB
  const int wid = threadIdx.x >> 6, lane = threadIdx.x & 63;
  if (threadIdx.x < 64) coefs[threadIdx.x] = coef1[threadIdx.x];
  __syncthreads();
  const int nbase = blockIdx.x * 16;
#pragma unroll
  for (int jn = 0; jn < 4; ++jn) {
    const int m = wid * 4 + jn;
    gather_node(rowp, s_edge, xbf, (const float4*)coefs, uA, nbase + m, m, lane);
  }
  __syncthreads();
  // MFMA1: wave wid handles o-tile wid (o = 16*wid .. +15); 2 slabs.
  const int nloc = lane & 15, kgrp = lane >> 4;
  f32x4 acc1 = {0.f, 0.f, 0.f, 0.f};
#pragma unroll
  for (int ks = 0; ks < 8; ++ks) {
    const int k0 = ks * 32 + kgrp * 8;
    const bf16x8 b = *(const bf16x8*)&b1T[(wid * 16 + nloc) * 256 + k0];
    const bf16x8 aS0 = *(const bf16x8*)&uA[(0 * 16 + nloc) * ROWB + k0];
    acc1 = __builtin_amdgcn_mfma_f32_16x16x32_bf16(aS0, b, acc1, 0, 0, 0);
    const bf16x8 aS1 = *(const bf16x8*)&uA[(1 * 16 + nloc) * ROWB + k0];
    acc1 = __builtin_amdgcn_mfma_f32_16x16x32_bf16(aS1, b, acc1, 0, 0, 0);
  }
  {
    const int o = wid * 16 + nloc;
    const float bs = bias1[o];
#pragma unroll
    for (int r = 0; r < 4; ++r) {
      const int m = (lane >> 4) * 4 + r;
      cmat[m * 68 + o] = fmaxf(acc1[r] + bs, 0.f);
    }
  }
  __syncthreads();
  // MFMA2: Y2 = h1 @ b2p. Wave wid handles j-tile wid (j = 16*wid .. +15).
  f32x4 acc2 = {0.f, 0.f, 0.f, 0.f};
#pragma unroll
  for (int ks = 0; ks < 2; ++ks) {
    const int k0 = ks * 32 + kgrp * 8;
    const float4 c0 = *(const float4*)&cmat[nloc * 68 + k0];
    const float4 c1 = *(const float4*)&cmat[nloc * 68 + k0 + 4];
    union { bf16x8 v; unsigned u[4]; } au;
    au.u[0] = packbf2(c0.x, c0.y); au.u[1] = packbf2(c0.z, c0.w);
    au.u[2] = packbf2(c1.x, c1.y); au.u[3] = packbf2(c1.z, c1.w);
    const bf16x8 b = *(const bf16x8*)&b2p[(wid * 16 + nloc) * 64 + k0];
    acc2 = __builtin_amdgcn_mfma_f32_16x16x32_bf16(au.v, b, acc2, 0, 0, 0);
  }
  __syncthreads();  // cmat reads done; reuse as Y2 staging
#pragma unroll
  for (int r = 0; r < 4; ++r) {
    const int m = (lane >> 4) * 4 + r;
    cmat[m * 68 + wid * 16 + nloc] = acc2[r];
  }
  __syncthreads();
  const int nl = threadIdx.x >> 4, c4 = threadIdx.x & 15;
  const float* cr = &cmat[nl * 68 + 4 * c4];
  y2bf[(size_t)(nbase + nl) * 16 + c4] =
      make_uint2(packbf2(cr[0], cr[1]), packbf2(cr[2], cr[3]));
}

// ===========================================================================
// Layer 2 (slim, widened):
// out[d][o] = relu(bias2[o] + sum_{e->d} nm_e * dot(coef2[t_e], Y2[src][o][:]))
// Wave = 2 nodes interleaved; lane = (eslot = lane>>3 in [0,8), og = lane&7).
// Each lane loads one uint4 (2 output channels x 4 bases) -> 8 edge streams.
// ===========================================================================
__global__ __launch_bounds__(256) void k_l2_gather(
    const int* __restrict__ rowp, const unsigned* __restrict__ s_edge,
    const uint4* __restrict__ y2v,   // [N][8] uint4
    const float* __restrict__ coef2, const float* __restrict__ bias2,
    float2* __restrict__ out) {      // [N][8] float2
  __shared__ float coefs[64];
  if (threadIdx.x < 64) coefs[threadIdx.x] = coef2[threadIdx.x];
  __syncthreads();
  const float4* coefv = (const float4*)coefs;
  const int wid = threadIdx.x >> 6, lane = threadIdx.x & 63;
  const int eslot = lane >> 3, og = lane & 7;
  const int nbase = blockIdx.x * 8 + wid * 2;

  int j[2], jend[2];
  float a0[2] = {0.f, 0.f}, a1[2] = {0.f, 0.f};
  unsigned r0[2], r1[2];
  uint4 yp[2];
#pragma unroll
  for (int m = 0; m < 2; ++m) {
    const int node = nbase + m;
    const int beg = rowp[node];
    jend[m] = rowp[node + 1];
    j[m] = beg + eslot;
    r0[m] = 0; r1[m] = 0;
    yp[m] = make_uint4(0, 0, 0, 0);
    if (j[m] < jend[m]) r0[m] = s_edge[j[m]];
    if (j[m] + 8 < jend[m]) r1[m] = s_edge[j[m] + 8];
  }
#pragma unroll
  for (int m = 0; m < 2; ++m)
    if (j[m] < jend[m]) yp[m] = y2v[(r0[m] & 0xFFFF) * 8 + og];

  while ((j[0] < jend[0]) | (j[1] < jend[1])) {
#pragma unroll
    for (int m = 0; m < 2; ++m) {
      unsigned r2 = 0;
      uint4 yp1 = make_uint4(0, 0, 0, 0);
      if (j[m] + 16 < jend[m]) r2 = s_edge[j[m] + 16];
      if (j[m] + 8 < jend[m]) yp1 = y2v[(r1[m] & 0xFFFF) * 8 + og];
      if (j[m] < jend[m]) {
        const float nm = (float)(r0[m] >> 20) * NMSCALE;
        const float4 c = coefv[(r0[m] >> 16) & 15];
        a0[m] += nm * (c.x * bflo(yp[m].x) + c.y * bfhi(yp[m].x) +
                       c.z * bflo(yp[m].y) + c.w * bfhi(yp[m].y));
        a1[m] += nm * (c.x * bflo(yp[m].z) + c.y * bfhi(yp[m].z) +
                       c.z * bflo(yp[m].w) + c.w * bfhi(yp[m].w));
      }
      j[m] += 8; r0[m] = r1[m]; r1[m] = r2; yp[m] = yp1;
    }
  }
#pragma unroll
  for (int m = 0; m < 2; ++m) {
    a0[m] += __shfl_down(a0[m], 32, 64);
    a0[m] += __shfl_down(a0[m], 16, 64);
    a0[m] += __shfl_down(a0[m], 8, 64);
    a1[m] += __shfl_down(a1[m], 32, 64);
    a1[m] += __shfl_down(a1[m], 16, 64);
    a1[m] += __shfl_down(a1[m], 8, 64);
  }
  if (eslot == 0) {
    const float b0 = bias2[2 * og], b1 = bias2[2 * og + 1];
#pragma unroll
    for (int m = 0; m < 2; ++m) {
      out[(size_t)(nbase + m) * 8 + og] =
          make_float2(fmaxf(a0[m] + b0, 0.f), fmaxf(a1[m] + b1, 0.f));
    }
  }
}

extern "C" void kernel_launch(void* const* d_in, const int* in_sizes, int n_in,
                              void* d_out, int out_size, void* d_ws, size_t ws_size,
                              hipStream_t stream) {
  const float* feats  = (const float*)d_in[0];
  const int*   src    = (const int*)d_in[1];
  const int*   dst    = (const int*)d_in[2];
  const int*   etype  = (const int*)d_in[3];
  const float* enorm  = (const float*)d_in[4];
  const float* bases1 = (const float*)d_in[5];
  const float* coef1  = (const float*)d_in[6];
  const float* bias1  = (const float*)d_in[7];
  const float* bases2 = (const float*)d_in[8];
  const float* coef2  = (const float*)d_in[9];
  const float* bias2  = (const float*)d_in[10];

  // Workspace (~20 MB): xbf | y2bf | s_edge (4 B recs) | rank | b1T | b2p
  //                     | deg | rowp | bsum
  uint2* xbf    = (uint2*)d_ws;                       // N*16 uint2 (6.4 MB)
  uint2* y2bf   = xbf + (size_t)N_NODES * 16;         // N*16 uint2 (6.4 MB)
  unsigned* s_edge = (unsigned*)(y2bf + (size_t)N_NODES * 16);  // E uint (3.2 MB)
  int*   rank   = (int*)(s_edge + N_EDGES);           // E ints (3.2 MB)
  unsigned short* b1T = (unsigned short*)(rank + N_EDGES);  // 16384 (32 KB)
  unsigned short* b2p = b1T + 64 * 256;               // 4096 (8 KB)
  int*   deg    = (int*)(b2p + 64 * 64);              // N
  int*   rowp   = deg + N_NODES;                      // N+1
  int*   bsum   = rowp + N_NODES + 1;                 // 64

  const int SCAN_BLKS = (N_NODES + 1023) / 1024;  // 49

  hipMemsetAsync(deg, 0, N_NODES * sizeof(int), stream);

  k_prep_hist<<<3126, 256, 0, stream>>>((const float4*)feats, xbf, bases1,
                                        bases2, b1T, b2p, dst, deg, rank);
  k_scan1<<<SCAN_BLKS, 1024, 0, stream>>>(deg, rowp, bsum);
  k_scan3<<<SCAN_BLKS, 1024, 0, stream>>>(rowp, bsum, SCAN_BLKS);
  k_scatter<<<N_EDGES / 256, 256, 0, stream>>>(src, dst, etype, enorm,
                                               rowp, rank, s_edge);
  k_l1_fused<<<N_NODES / 16, 256, 0, stream>>>(rowp, s_edge, xbf, coef1,
                                               b1T, bias1, b2p, y2bf);
  k_l2_gather<<<N_NODES / 8, 256, 0, stream>>>(rowp, s_edge,
                                               (const uint4*)y2bf, coef2,
                                               bias2, (float2*)d_out);
}